// Round 8
// baseline (129.835 us; speedup 1.0000x reference)
//
#include <hip/hip_runtime.h>
#include <math.h>

#define PCK_STRIDE 416
#define N_SAMPLES  32768
#define FFT_M      16384        // complex FFT size (real packing)
#define B_EVENTS   128
#define N_GROUPS   16
#define NT         1024
#define PI_F 3.14159265358979323846f
#define RT2H 0.70710678118654752f   // sqrt(2)/2

// LDS padded mapping: +4 floats per 32-block (keeps 8-blocks contiguous and
// 16B-aligned; all r4/r8 accesses <=2-way bank aliasing).
#define MAP(i) ((i) + (((i) >> 5) << 2))
#define LDS_N  18432            // 16384 + 2048 pad

__device__ inline float filt_at(const float* __restrict__ f, int k) {
    if (k >= FFT_M) return 0.0f;
    float c = ((float)k + 0.5f) * (1.0f / 1024.0f) - 0.5f;
    c = fminf(fmaxf(c, 0.0f), 15.0f);
    int i0 = (int)floorf(c);
    int i1 = min(i0 + 1, 15);
    float w = c - (float)i0;
    return f[i0] * (1.0f - w) + f[i1] * w;
}

// ---------------- radix-4 LDS stages (unroll 2: cap live range) ----------------
template<int L>
__device__ inline void r4_dif_stage(float* re, float* im, int tid) {
    constexpr int q = L >> 2;
    constexpr float ang = -6.28318530717958647692f / (float)L;
    #pragma unroll 2
    for (int s = 0; s < (FFT_M / 4) / NT; ++s) {
        int m = tid + s * NT;
        int t = m & (q - 1);
        int i0 = ((m & ~(q - 1)) << 2) | t;
        int ia = MAP(i0), ib = MAP(i0 + q), ic = MAP(i0 + 2 * q), id = MAP(i0 + 3 * q);
        float ar = re[ia], ai = im[ia];
        float br = re[ib], bi = im[ib];
        float cr = re[ic], ci = im[ic];
        float dr = re[id], di = im[id];
        float s1, c1; __sincosf(ang * (float)t, &s1, &c1);
        float c2 = c1 * c1 - s1 * s1, s2 = 2.0f * c1 * s1;
        float c3 = c2 * c1 - s2 * s1, s3 = c2 * s1 + s2 * c1;
        float s0r = ar + cr, s0i = ai + ci;
        float t1r = br + dr, t1i = bi + di;
        float d0r = ar - cr, d0i = ai - ci;
        float d1r = br - dr, d1i = bi - di;
        re[ia] = s0r + t1r; im[ia] = s0i + t1i;
        float er = s0r - t1r, ei = s0i - t1i;
        re[ib] = er * c2 - ei * s2; im[ib] = er * s2 + ei * c2;
        float fr = d0r + d1i, fi = d0i - d1r;   // (a-c) - i(b-d)
        re[ic] = fr * c1 - fi * s1; im[ic] = fr * s1 + fi * c1;
        float gr = d0r - d1i, gi = d0i + d1r;   // (a-c) + i(b-d)
        re[id] = gr * c3 - gi * s3; im[id] = gr * s3 + gi * c3;
    }
    __syncthreads();
}

template<int L>
__device__ inline void r4_dit_stage(float* re, float* im, int tid) {
    constexpr int q = L >> 2;
    constexpr float ang = 6.28318530717958647692f / (float)L;
    #pragma unroll 2
    for (int s = 0; s < (FFT_M / 4) / NT; ++s) {
        int m = tid + s * NT;
        int t = m & (q - 1);
        int i0 = ((m & ~(q - 1)) << 2) | t;
        int ia = MAP(i0), ib = MAP(i0 + q), ic = MAP(i0 + 2 * q), id = MAP(i0 + 3 * q);
        float ar = re[ia], ai = im[ia];
        float br = re[ib], bi = im[ib];
        float cr = re[ic], ci = im[ic];
        float dr = re[id], di = im[id];
        float s1, c1; __sincosf(ang * (float)t, &s1, &c1);
        float c2 = c1 * c1 - s1 * s1, s2 = 2.0f * c1 * s1;
        float tbr = br * c2 - bi * s2, tbi = br * s2 + bi * c2;
        float tdr = dr * c2 - di * s2, tdi = dr * s2 + di * c2;
        float B0r = ar + tbr, B0i = ai + tbi;
        float B1r = ar - tbr, B1i = ai - tbi;
        float B2r = cr + tdr, B2i = ci + tdi;
        float B3r = cr - tdr, B3i = ci - tdi;
        float t0r = B2r * c1 - B2i * s1, t0i = B2r * s1 + B2i * c1;
        float t1r = -B3r * s1 - B3i * c1, t1i = B3r * c1 - B3i * s1;  // B3*(i*w1)
        re[ia] = B0r + t0r; im[ia] = B0i + t0i;
        re[ib] = B1r + t1r; im[ib] = B1i + t1i;
        re[ic] = B0r - t0r; im[ic] = B0i - t0i;
        re[id] = B1r - t1r; im[id] = B1i - t1i;
    }
    __syncthreads();
}

// ---------------- K2: 16384-pt complex FFT filter + fused prep (wave 0) ----------------
// waves_per_eu(4,4): NT=1024 -> 16 waves/CU (4/EU), VGPR budget 128 >= the
// ~88 this kernel needs (R7 measured), so no spill; 2x latency hiding vs R7.
__global__ __launch_bounds__(NT)
__attribute__((amdgpu_waves_per_eu(4, 4)))
void fft_filter_kernel(
    const float* __restrict__ noise, const float* __restrict__ packed,
    const float* __restrict__ gamp, float* __restrict__ noise_out,
    const float* __restrict__ freqs, float* __restrict__ rW, float* __restrict__ res)
{
    extern __shared__ float smem[];
    float* re = smem;
    float* im = smem + LDS_N;
    float* filt = smem + 2 * LDS_N;
    const int b = blockIdx.x;
    const int tid = threadIdx.x;
    const float g = gamp[0];

    // --- load + fused r2 DIF (half=8192) ---
    const float2* nz = (const float2*)(noise + (size_t)b * N_SAMPLES);
    #pragma unroll 4
    for (int s = 0; s < 8192 / NT; ++s) {
        int j = tid + s * NT;
        float2 v0 = nz[j];
        float2 v1 = nz[j + 8192];
        float ur = v0.x * g, ui = v0.y * g;
        float wr = v1.x * g, wi = v1.y * g;
        float s1, c1; __sincosf((-PI_F / 8192.0f) * (float)j, &s1, &c1);
        int a0 = MAP(j), a1 = MAP(j + 8192);
        re[a0] = ur + wr; im[a0] = ui + wi;
        float dr = ur - wr, di = ui - wi;
        re[a1] = dr * c1 - di * s1;
        im[a1] = dr * s1 + di * c1;
    }
    if (tid >= 64 && tid < 80) filt[tid - 64] = packed[b * PCK_STRIDE + 400 + (tid - 64)];

    // --- fused prep on wave 0 (shuffle-only, no extra barriers) ---
    if (tid < 64) {
        const float* row = packed + b * PCK_STRIDE;
        float n0 = row[tid], n1 = row[tid + 64];
        float fq0 = freqs[tid], fq1 = freqs[tid + 64];
        float mx = fmaxf(n0, n1);
        #pragma unroll
        for (int off = 32; off >= 1; off >>= 1) mx = fmaxf(mx, __shfl_xor(mx, off));
        float e0 = __expf(n0 - mx), e1 = __expf(n1 - mx);
        float den = e0 + e1, num = e0 * fq0 + e1 * fq1;
        #pragma unroll
        for (int off = 32; off >= 1; off >>= 1) {
            den += __shfl_xor(den, off);
            num += __shfl_xor(num, off);
        }
        float ampA = row[256 + tid] * 2.0f - 1.0f;   // frames 0..63
        float ampB = row[320 + tid] * 2.0f - 1.0f;   // frames 64..127
        int h = tid & 7;                              // lanes 8..63 mirror 0..7
        float ha = row[384 + h];
        float hd = 0.5f + row[392 + h] * 0.5f;
        const float MIN_F0 = 40.0f / 11025.0f;
        const float F0_SPAN = 3000.0f / 11025.0f - 40.0f / 11025.0f;
        float f0s = num / den;
        float f0 = MIN_F0 + f0s * f0s * 11025.0f * F0_SPAN;
        float r = f0 * (float)(h + 1) * (PI_F / 11025.0f);
        if (r >= PI_F) r = 0.0f;
        if (tid < 8) rW[b * 8 + tid] = r;
        float cur = 0.0f;
        float* rr = res + (b * 8 + h) * 128;
        for (int f = 0; f < 64; ++f) {
            float av = __shfl(ampA, f);
            float c = fmaxf(cur + av * ha, 0.0f);
            if (tid < 8) rr[f] = c;
            cur = c * hd;
        }
        for (int f = 0; f < 64; ++f) {
            float av = __shfl(ampB, f);
            float c = fmaxf(cur + av * ha, 0.0f);
            if (tid < 8) rr[64 + f] = c;
            cur = c * hd;
        }
    }
    __syncthreads();

    // --- radix-4 DIF stages ---
    r4_dif_stage<8192>(re, im, tid);
    r4_dif_stage<2048>(re, im, tid);
    r4_dif_stage<512>(re, im, tid);
    r4_dif_stage<128>(re, im, tid);
    r4_dif_stage<32>(re, im, tid);

    // --- register radix-8 DIF (half=4,2,1), scalar vars, float4 LDS I/O ---
    #pragma unroll 2
    for (int s = 0; s < 2048 / NT; ++s) {
        int m = (2048 / NT) * tid + s;
        int a = MAP(8 * m);
        float4 r0 = *(const float4*)(re + a);
        float4 r1 = *(const float4*)(re + a + 4);
        float4 q0 = *(const float4*)(im + a);
        float4 q1 = *(const float4*)(im + a + 4);
        // half=4
        float t0r = r0.x + r1.x, t0i = q0.x + q1.x;
        float u0r = r0.x - r1.x, u0i = q0.x - q1.x;
        float d1r = r0.y - r1.y, d1i = q0.y - q1.y;
        float t1r = r0.y + r1.y, t1i = q0.y + q1.y;
        float u1r = RT2H * (d1r + d1i), u1i = RT2H * (d1i - d1r);   // *(c-ci)
        float t2r = r0.z + r1.z, t2i = q0.z + q1.z;
        float d2r = r0.z - r1.z, d2i = q0.z - q1.z;
        float u2r = d2i, u2i = -d2r;                                  // *(-i)
        float t3r = r0.w + r1.w, t3i = q0.w + q1.w;
        float d3r = r0.w - r1.w, d3i = q0.w - q1.w;
        float u3r = RT2H * (d3i - d3r), u3i = -RT2H * (d3r + d3i);  // *(-c-ci)
        // half=2
        float A0r = t0r + t2r, A0i = t0i + t2i;
        float A2r = t0r - t2r, A2i = t0i - t2i;
        float A1r = t1r + t3r, A1i = t1i + t3i;
        float e3r = t1r - t3r, e3i = t1i - t3i;
        float A3r = e3i, A3i = -e3r;                                  // *(-i)
        float B0r = u0r + u2r, B0i = u0i + u2i;
        float B2r = u0r - u2r, B2i = u0i - u2i;
        float B1r = u1r + u3r, B1i = u1i + u3i;
        float f3r = u1r - u3r, f3i = u1i - u3i;
        float B3r = f3i, B3i = -f3r;
        // half=1
        r0.x = A0r + A1r; q0.x = A0i + A1i;
        r0.y = A0r - A1r; q0.y = A0i - A1i;
        r0.z = A2r + A3r; q0.z = A2i + A3i;
        r0.w = A2r - A3r; q0.w = A2i - A3i;
        r1.x = B0r + B1r; q1.x = B0i + B1i;
        r1.y = B0r - B1r; q1.y = B0i - B1i;
        r1.z = B2r + B3r; q1.z = B2i + B3i;
        r1.w = B2r - B3r; q1.w = B2i - B3i;
        *(float4*)(re + a) = r0; *(float4*)(re + a + 4) = r1;
        *(float4*)(im + a) = q0; *(float4*)(im + a + 4) = q1;
    }
    __syncthreads();

    // --- pointwise untangle * H * retangle, bitrev domain ---
    const float invM = 1.0f / (float)FFT_M;
    #pragma unroll 2
    for (int s = 0; s < 8192 / NT; ++s) {
        int jj = (tid + s * NT) << 1;       // even position
        if (jj == 0) {
            int p0 = MAP(0);
            float z0r = re[p0], z0i = im[p0];
            float y = 0.5f * filt_at(filt, 0) * (z0r + z0i) * invM;
            re[p0] = y; im[p0] = y;
            int p1 = MAP(1);                  // k=8192 self-pair at brev(8192)=1
            float H = filt_at(filt, 8192) * invM;
            re[p1] *= H; im[p1] *= H;
        } else {
            int k = (int)(__brev((unsigned)jj) >> 18);     // k in [1,8192)
            int kq = FFT_M - k;
            int pk = MAP(jj);
            int pq = MAP((int)(__brev((unsigned)kq) >> 18));
            float zkr = re[pk], zki = im[pk];
            float zqr = re[pq], zqi = im[pq];
            float Er = 0.5f * (zkr + zqr), Ei = 0.5f * (zki - zqi);
            float Or = 0.5f * (zki + zqi), Oi = 0.5f * (zqr - zkr);
            float th = (float)k * (PI_F / (float)FFT_M);
            float s1, c1; __sincosf(th, &s1, &c1);
            float ts = -s1;
            float tOr = c1 * Or - ts * Oi;
            float tOi = c1 * Oi + ts * Or;
            float Hk = filt_at(filt, k);
            float Hq = filt_at(filt, kq);
            float Ykr = Hk * (Er + tOr), Yki = Hk * (Ei + tOi);
            float Cr  = Hq * (Er - tOr), Ci  = Hq * (Ei - tOi);
            float Ar = 0.5f * (Ykr + Cr), Ai = 0.5f * (Yki + Ci);
            float Br = 0.5f * (Ykr - Cr), Bi = 0.5f * (Yki - Ci);
            re[pk] = (Ar + ts * Br - c1 * Bi) * invM;
            im[pk] = (Ai + c1 * Br + ts * Bi) * invM;
            re[pq] = (Ar + c1 * Bi - ts * Br) * invM;
            im[pq] = (-Ai + c1 * Br + ts * Bi) * invM;
        }
    }
    __syncthreads();

    // --- register radix-8 DIT (half=1,2,4), scalar vars ---
    #pragma unroll 2
    for (int s = 0; s < 2048 / NT; ++s) {
        int m = (2048 / NT) * tid + s;
        int a = MAP(8 * m);
        float4 r0 = *(const float4*)(re + a);
        float4 r1 = *(const float4*)(re + a + 4);
        float4 q0 = *(const float4*)(im + a);
        float4 q1 = *(const float4*)(im + a + 4);
        // half=1
        float A0r = r0.x + r0.y, A0i = q0.x + q0.y;
        float A1r = r0.x - r0.y, A1i = q0.x - q0.y;
        float A2r = r0.z + r0.w, A2i = q0.z + q0.w;
        float A3r = r0.z - r0.w, A3i = q0.z - q0.w;
        float B0r = r1.x + r1.y, B0i = q1.x + q1.y;
        float B1r = r1.x - r1.y, B1i = q1.x - q1.y;
        float B2r = r1.z + r1.w, B2i = q1.z + q1.w;
        float B3r = r1.z - r1.w, B3i = q1.z - q1.w;
        // half=2 ; twiddle on odd: *(+i)
        float t0r = A0r + A2r, t0i = A0i + A2i;
        float t2r = A0r - A2r, t2i = A0i - A2i;
        float w3r = -A3i, w3i = A3r;
        float t1r = A1r + w3r, t1i = A1i + w3i;
        float t3r = A1r - w3r, t3i = A1i - w3i;
        float u0r = B0r + B2r, u0i = B0i + B2i;
        float u2r = B0r - B2r, u2i = B0i - B2i;
        float x3r = -B3i, x3i = B3r;
        float u1r = B1r + x3r, u1i = B1i + x3i;
        float u3r = B1r - x3r, u3i = B1i - x3i;
        // half=4 ; twiddles 1, c(1+i), +i, c(-1+i)
        float w1r = RT2H * (u1r - u1i), w1i = RT2H * (u1r + u1i);
        float w2r = -u2i,               w2i = u2r;
        float w5r = RT2H * (-u3r - u3i), w5i = RT2H * (u3r - u3i);
        r0.x = t0r + u0r; q0.x = t0i + u0i;
        r1.x = t0r - u0r; q1.x = t0i - u0i;
        r0.y = t1r + w1r; q0.y = t1i + w1i;
        r1.y = t1r - w1r; q1.y = t1i - w1i;
        r0.z = t2r + w2r; q0.z = t2i + w2i;
        r1.z = t2r - w2r; q1.z = t2i - w2i;
        r0.w = t3r + w5r; q0.w = t3i + w5i;
        r1.w = t3r - w5r; q1.w = t3i - w5i;
        *(float4*)(re + a) = r0; *(float4*)(re + a + 4) = r1;
        *(float4*)(im + a) = q0; *(float4*)(im + a + 4) = q1;
    }
    __syncthreads();

    // --- radix-4 DIT stages ---
    r4_dit_stage<32>(re, im, tid);
    r4_dit_stage<128>(re, im, tid);
    r4_dit_stage<512>(re, im, tid);
    r4_dit_stage<2048>(re, im, tid);
    r4_dit_stage<8192>(re, im, tid);

    // --- fused final r2 DIT (half=8192) + store ---
    float2* oz = (float2*)(noise_out + (size_t)b * N_SAMPLES);
    #pragma unroll 4
    for (int s = 0; s < 8192 / NT; ++s) {
        int j = tid + s * NT;
        int a0 = MAP(j), a1 = MAP(j + 8192);
        float ur = re[a0], ui = im[a0];
        float xr = re[a1], xi = im[a1];
        float s1, c1; __sincosf((PI_F / 8192.0f) * (float)j, &s1, &c1);
        float wr = xr * c1 - xi * s1, wi = xr * s1 + xi * c1;
        oz[j] = make_float2(ur + wr, ui + wi);
        oz[j + 8192] = make_float2(ur - wr, ui - wi);
    }
}

// ---------------- K3: gate noise, add harmonic bank, sum 8 events ----------------
// Chebyshev: r_h = h*r_1, so sin((n+1)*r_h) = U-recurrence from one sincos.
__global__ __launch_bounds__(256) void assemble_kernel(
    const float* __restrict__ packed, const float* __restrict__ rW,
    const float* __restrict__ res, const float* __restrict__ noise_out,
    const float* __restrict__ oamp, float* __restrict__ out)
{
    const int g = blockIdx.y;
    const int chunk = blockIdx.x;
    const int tid = threadIdx.x;
    const int n = chunk * 256 + tid;
    const int fb = chunk - 1;

    __shared__ float s_res[8][8][3];
    __shared__ float s_ampf[8][3];
    __shared__ float s_r[8][8];
    if (tid < 192) {
        int e = tid / 24, rem = tid % 24, h = rem / 3, j = rem % 3;
        int f = min(max(fb + j, 0), 127);
        s_res[e][h][j] = res[((g * 8 + e) * 8 + h) * 128 + f];
    }
    if (tid < 24) {
        int e = tid / 3, j = tid % 3;
        int f = min(max(fb + j, 0), 127);
        s_ampf[e][j] = packed[(g * 8 + e) * PCK_STRIDE + 256 + f] * 2.0f - 1.0f;
    }
    if (tid >= 192 && tid < 256) {
        int u = tid - 192;
        s_r[u / 8][u % 8] = rW[g * 64 + u];
    }
    __syncthreads();

    float coords = ((float)n + 0.5f) * (1.0f / 256.0f) - 0.5f;
    coords = fminf(fmaxf(coords, 0.0f), 127.0f);
    int i0 = (int)floorf(coords);
    float w = coords - (float)i0;
    int j0 = i0 - fb;
    float osc50 = oamp[0];
    float pn = (float)(n + 1);
    float wm = 1.0f - w;

    float acc = 0.0f;
    #pragma unroll
    for (int e = 0; e < 8; ++e) {
        int b = g * 8 + e;
        float nv = noise_out[(size_t)b * N_SAMPLES + n];
        float av = s_ampf[e][j0] * wm + s_ampf[e][j0 + 1] * w;
        float gate = (av >= 0.0f) ? av : 0.2f * av;
        acc += nv * gate;
        float sn, cn; __sincosf(pn * s_r[e][0], &sn, &cn);
        float c2 = 2.0f * cn;
        float shm1 = 0.0f, sh = sn;
        #pragma unroll
        for (int h = 0; h < 8; ++h) {
            float rsv = s_res[e][h][j0] * wm + s_res[e][h][j0 + 1] * w;
            float sv = (s_r[e][h] != 0.0f) ? sh : 0.0f;
            acc += rsv * osc50 * sv;
            float nx = c2 * sh - shm1;
            shm1 = sh; sh = nx;
        }
    }
    out[(size_t)g * N_SAMPLES + n] = acc;
}

extern "C" void kernel_launch(void* const* d_in, const int* in_sizes, int n_in,
                              void* d_out, int out_size, void* d_ws, size_t ws_size,
                              hipStream_t stream) {
    const float* packed = (const float*)d_in[0];
    const float* freqs  = (const float*)d_in[1];
    const float* gamp   = (const float*)d_in[2];
    const float* oamp   = (const float*)d_in[3];
    const float* noise  = (const float*)d_in[4];
    float* out = (float*)d_out;

    float* ws = (float*)d_ws;
    float* noise_out = ws;
    float* res = ws + (size_t)B_EVENTS * N_SAMPLES;
    float* rW  = res + B_EVENTS * 8 * 128;

    fft_filter_kernel<<<B_EVENTS, NT, (2 * LDS_N + 16) * sizeof(float), stream>>>(
        noise, packed, gamp, noise_out, freqs, rW, res);
    assemble_kernel<<<dim3(N_SAMPLES / 256, N_GROUPS), 256, 0, stream>>>(
        packed, rW, res, noise_out, oamp, out);
}

// Round 9
// 117.797 us; speedup vs baseline: 1.1022x; 1.1022x over previous
//
#include <hip/hip_runtime.h>
#include <math.h>

#define PCK_STRIDE 416
#define N_SAMPLES  32768
#define FFT_M      16384        // complex FFT size (real packing)
#define B_EVENTS   128
#define N_GROUPS   16
#define NT         1024
#define PI_F 3.14159265358979323846f
#define RT2H 0.70710678118654752f   // sqrt(2)/2

// LDS padded mapping: +4 floats per 32-block (keeps 8-blocks contiguous and
// 16B-aligned; all r4/r8 accesses <=2-way bank aliasing).
#define MAP(i) ((i) + (((i) >> 5) << 2))
#define LDS_N  18432            // 16384 + 2048 pad

__device__ inline float filt_at(const float* __restrict__ f, int k) {
    if (k >= FFT_M) return 0.0f;
    float c = ((float)k + 0.5f) * (1.0f / 1024.0f) - 0.5f;
    c = fminf(fmaxf(c, 0.0f), 15.0f);
    int i0 = (int)floorf(c);
    int i1 = min(i0 + 1, 15);
    float w = c - (float)i0;
    return f[i0] * (1.0f - w) + f[i1] * w;
}

// ---------------- radix-4 LDS stages ----------------
// unroll 1: peak live range ~40 floats so the kernel fits the 64-VGPR budget
// the allocator pins for 1024-thread blocks (R6/R8 evidence: attributes can't
// raise it; spills cost ~25 MB HBM round-trip). 16 waves/CU supply the ILP.
template<int L>
__device__ inline void r4_dif_stage(float* re, float* im, int tid) {
    constexpr int q = L >> 2;
    constexpr float ang = -6.28318530717958647692f / (float)L;
    #pragma unroll 1
    for (int s = 0; s < (FFT_M / 4) / NT; ++s) {
        int m = tid + s * NT;
        int t = m & (q - 1);
        int i0 = ((m & ~(q - 1)) << 2) | t;
        int ia = MAP(i0), ib = MAP(i0 + q), ic = MAP(i0 + 2 * q), id = MAP(i0 + 3 * q);
        float ar = re[ia], ai = im[ia];
        float br = re[ib], bi = im[ib];
        float cr = re[ic], ci = im[ic];
        float dr = re[id], di = im[id];
        float s1, c1; __sincosf(ang * (float)t, &s1, &c1);
        float c2 = c1 * c1 - s1 * s1, s2 = 2.0f * c1 * s1;
        float c3 = c2 * c1 - s2 * s1, s3 = c2 * s1 + s2 * c1;
        float s0r = ar + cr, s0i = ai + ci;
        float t1r = br + dr, t1i = bi + di;
        float d0r = ar - cr, d0i = ai - ci;
        float d1r = br - dr, d1i = bi - di;
        re[ia] = s0r + t1r; im[ia] = s0i + t1i;
        float er = s0r - t1r, ei = s0i - t1i;
        re[ib] = er * c2 - ei * s2; im[ib] = er * s2 + ei * c2;
        float fr = d0r + d1i, fi = d0i - d1r;   // (a-c) - i(b-d)
        re[ic] = fr * c1 - fi * s1; im[ic] = fr * s1 + fi * c1;
        float gr = d0r - d1i, gi = d0i + d1r;   // (a-c) + i(b-d)
        re[id] = gr * c3 - gi * s3; im[id] = gr * s3 + gi * c3;
    }
    __syncthreads();
}

template<int L>
__device__ inline void r4_dit_stage(float* re, float* im, int tid) {
    constexpr int q = L >> 2;
    constexpr float ang = 6.28318530717958647692f / (float)L;
    #pragma unroll 1
    for (int s = 0; s < (FFT_M / 4) / NT; ++s) {
        int m = tid + s * NT;
        int t = m & (q - 1);
        int i0 = ((m & ~(q - 1)) << 2) | t;
        int ia = MAP(i0), ib = MAP(i0 + q), ic = MAP(i0 + 2 * q), id = MAP(i0 + 3 * q);
        float ar = re[ia], ai = im[ia];
        float br = re[ib], bi = im[ib];
        float cr = re[ic], ci = im[ic];
        float dr = re[id], di = im[id];
        float s1, c1; __sincosf(ang * (float)t, &s1, &c1);
        float c2 = c1 * c1 - s1 * s1, s2 = 2.0f * c1 * s1;
        float tbr = br * c2 - bi * s2, tbi = br * s2 + bi * c2;
        float tdr = dr * c2 - di * s2, tdi = dr * s2 + di * c2;
        float B0r = ar + tbr, B0i = ai + tbi;
        float B1r = ar - tbr, B1i = ai - tbi;
        float B2r = cr + tdr, B2i = ci + tdi;
        float B3r = cr - tdr, B3i = ci - tdi;
        float t0r = B2r * c1 - B2i * s1, t0i = B2r * s1 + B2i * c1;
        float t1r = -B3r * s1 - B3i * c1, t1i = B3r * c1 - B3i * s1;  // B3*(i*w1)
        re[ia] = B0r + t0r; im[ia] = B0i + t0i;
        re[ib] = B1r + t1r; im[ib] = B1i + t1i;
        re[ic] = B0r - t0r; im[ic] = B0i - t0i;
        re[id] = B1r - t1r; im[id] = B1i - t1i;
    }
    __syncthreads();
}

// ---------------- K2: 16384-pt complex FFT filter + fused prep (wave 0) ----------------
__global__ __launch_bounds__(NT)
void fft_filter_kernel(
    const float* __restrict__ noise, const float* __restrict__ packed,
    const float* __restrict__ gamp, float* __restrict__ noise_out,
    const float* __restrict__ freqs, float* __restrict__ rW, float* __restrict__ res)
{
    extern __shared__ float smem[];
    float* re = smem;
    float* im = smem + LDS_N;
    float* filt = smem + 2 * LDS_N;
    const int b = blockIdx.x;
    const int tid = threadIdx.x;
    const float g = gamp[0];

    // --- load + fused r2 DIF (half=8192) ---
    const float2* nz = (const float2*)(noise + (size_t)b * N_SAMPLES);
    #pragma unroll 1
    for (int s = 0; s < 8192 / NT; ++s) {
        int j = tid + s * NT;
        float2 v0 = nz[j];
        float2 v1 = nz[j + 8192];
        float ur = v0.x * g, ui = v0.y * g;
        float wr = v1.x * g, wi = v1.y * g;
        float s1, c1; __sincosf((-PI_F / 8192.0f) * (float)j, &s1, &c1);
        int a0 = MAP(j), a1 = MAP(j + 8192);
        re[a0] = ur + wr; im[a0] = ui + wi;
        float dr = ur - wr, di = ui - wi;
        re[a1] = dr * c1 - di * s1;
        im[a1] = dr * s1 + di * c1;
    }
    if (tid >= 64 && tid < 80) filt[tid - 64] = packed[b * PCK_STRIDE + 400 + (tid - 64)];

    // --- fused prep on wave 0 (shuffle-only, no extra barriers) ---
    if (tid < 64) {
        const float* row = packed + b * PCK_STRIDE;
        float n0 = row[tid], n1 = row[tid + 64];
        float fq0 = freqs[tid], fq1 = freqs[tid + 64];
        float mx = fmaxf(n0, n1);
        #pragma unroll
        for (int off = 32; off >= 1; off >>= 1) mx = fmaxf(mx, __shfl_xor(mx, off));
        float e0 = __expf(n0 - mx), e1 = __expf(n1 - mx);
        float den = e0 + e1, num = e0 * fq0 + e1 * fq1;
        #pragma unroll
        for (int off = 32; off >= 1; off >>= 1) {
            den += __shfl_xor(den, off);
            num += __shfl_xor(num, off);
        }
        float ampA = row[256 + tid] * 2.0f - 1.0f;   // frames 0..63
        float ampB = row[320 + tid] * 2.0f - 1.0f;   // frames 64..127
        int h = tid & 7;                              // lanes 8..63 mirror 0..7
        float ha = row[384 + h];
        float hd = 0.5f + row[392 + h] * 0.5f;
        const float MIN_F0 = 40.0f / 11025.0f;
        const float F0_SPAN = 3000.0f / 11025.0f - 40.0f / 11025.0f;
        float f0s = num / den;
        float f0 = MIN_F0 + f0s * f0s * 11025.0f * F0_SPAN;
        float r = f0 * (float)(h + 1) * (PI_F / 11025.0f);
        if (r >= PI_F) r = 0.0f;
        if (tid < 8) rW[b * 8 + tid] = r;
        float cur = 0.0f;
        float* rr = res + (b * 8 + h) * 128;
        for (int f = 0; f < 64; ++f) {
            float av = __shfl(ampA, f);
            float c = fmaxf(cur + av * ha, 0.0f);
            if (tid < 8) rr[f] = c;
            cur = c * hd;
        }
        for (int f = 0; f < 64; ++f) {
            float av = __shfl(ampB, f);
            float c = fmaxf(cur + av * ha, 0.0f);
            if (tid < 8) rr[64 + f] = c;
            cur = c * hd;
        }
    }
    __syncthreads();

    // --- radix-4 DIF stages ---
    r4_dif_stage<8192>(re, im, tid);
    r4_dif_stage<2048>(re, im, tid);
    r4_dif_stage<512>(re, im, tid);
    r4_dif_stage<128>(re, im, tid);
    r4_dif_stage<32>(re, im, tid);

    // --- register radix-8 DIF (half=4,2,1), scalar vars, float4 LDS I/O ---
    #pragma unroll 1
    for (int s = 0; s < 2048 / NT; ++s) {
        int m = (2048 / NT) * tid + s;
        int a = MAP(8 * m);
        float4 r0 = *(const float4*)(re + a);
        float4 r1 = *(const float4*)(re + a + 4);
        float4 q0 = *(const float4*)(im + a);
        float4 q1 = *(const float4*)(im + a + 4);
        // half=4
        float t0r = r0.x + r1.x, t0i = q0.x + q1.x;
        float u0r = r0.x - r1.x, u0i = q0.x - q1.x;
        float d1r = r0.y - r1.y, d1i = q0.y - q1.y;
        float t1r = r0.y + r1.y, t1i = q0.y + q1.y;
        float u1r = RT2H * (d1r + d1i), u1i = RT2H * (d1i - d1r);   // *(c-ci)
        float t2r = r0.z + r1.z, t2i = q0.z + q1.z;
        float d2r = r0.z - r1.z, d2i = q0.z - q1.z;
        float u2r = d2i, u2i = -d2r;                                  // *(-i)
        float t3r = r0.w + r1.w, t3i = q0.w + q1.w;
        float d3r = r0.w - r1.w, d3i = q0.w - q1.w;
        float u3r = RT2H * (d3i - d3r), u3i = -RT2H * (d3r + d3i);  // *(-c-ci)
        // half=2
        float A0r = t0r + t2r, A0i = t0i + t2i;
        float A2r = t0r - t2r, A2i = t0i - t2i;
        float A1r = t1r + t3r, A1i = t1i + t3i;
        float e3r = t1r - t3r, e3i = t1i - t3i;
        float A3r = e3i, A3i = -e3r;                                  // *(-i)
        float B0r = u0r + u2r, B0i = u0i + u2i;
        float B2r = u0r - u2r, B2i = u0i - u2i;
        float B1r = u1r + u3r, B1i = u1i + u3i;
        float f3r = u1r - u3r, f3i = u1i - u3i;
        float B3r = f3i, B3i = -f3r;
        // half=1
        r0.x = A0r + A1r; q0.x = A0i + A1i;
        r0.y = A0r - A1r; q0.y = A0i - A1i;
        r0.z = A2r + A3r; q0.z = A2i + A3i;
        r0.w = A2r - A3r; q0.w = A2i - A3i;
        r1.x = B0r + B1r; q1.x = B0i + B1i;
        r1.y = B0r - B1r; q1.y = B0i - B1i;
        r1.z = B2r + B3r; q1.z = B2i + B3i;
        r1.w = B2r - B3r; q1.w = B2i - B3i;
        *(float4*)(re + a) = r0; *(float4*)(re + a + 4) = r1;
        *(float4*)(im + a) = q0; *(float4*)(im + a + 4) = q1;
    }
    __syncthreads();

    // --- pointwise untangle * H * retangle, bitrev domain ---
    const float invM = 1.0f / (float)FFT_M;
    #pragma unroll 1
    for (int s = 0; s < 8192 / NT; ++s) {
        int jj = (tid + s * NT) << 1;       // even position
        if (jj == 0) {
            int p0 = MAP(0);
            float z0r = re[p0], z0i = im[p0];
            float y = 0.5f * filt_at(filt, 0) * (z0r + z0i) * invM;
            re[p0] = y; im[p0] = y;
            int p1 = MAP(1);                  // k=8192 self-pair at brev(8192)=1
            float H = filt_at(filt, 8192) * invM;
            re[p1] *= H; im[p1] *= H;
        } else {
            int k = (int)(__brev((unsigned)jj) >> 18);     // k in [1,8192)
            int kq = FFT_M - k;
            int pk = MAP(jj);
            int pq = MAP((int)(__brev((unsigned)kq) >> 18));
            float zkr = re[pk], zki = im[pk];
            float zqr = re[pq], zqi = im[pq];
            float Er = 0.5f * (zkr + zqr), Ei = 0.5f * (zki - zqi);
            float Or = 0.5f * (zki + zqi), Oi = 0.5f * (zqr - zkr);
            float th = (float)k * (PI_F / (float)FFT_M);
            float s1, c1; __sincosf(th, &s1, &c1);
            float ts = -s1;
            float tOr = c1 * Or - ts * Oi;
            float tOi = c1 * Oi + ts * Or;
            float Hk = filt_at(filt, k);
            float Hq = filt_at(filt, kq);
            float Ykr = Hk * (Er + tOr), Yki = Hk * (Ei + tOi);
            float Cr  = Hq * (Er - tOr), Ci  = Hq * (Ei - tOi);
            float Ar = 0.5f * (Ykr + Cr), Ai = 0.5f * (Yki + Ci);
            float Br = 0.5f * (Ykr - Cr), Bi = 0.5f * (Yki - Ci);
            re[pk] = (Ar + ts * Br - c1 * Bi) * invM;
            im[pk] = (Ai + c1 * Br + ts * Bi) * invM;
            re[pq] = (Ar + c1 * Bi - ts * Br) * invM;
            im[pq] = (-Ai + c1 * Br + ts * Bi) * invM;
        }
    }
    __syncthreads();

    // --- register radix-8 DIT (half=1,2,4), scalar vars ---
    #pragma unroll 1
    for (int s = 0; s < 2048 / NT; ++s) {
        int m = (2048 / NT) * tid + s;
        int a = MAP(8 * m);
        float4 r0 = *(const float4*)(re + a);
        float4 r1 = *(const float4*)(re + a + 4);
        float4 q0 = *(const float4*)(im + a);
        float4 q1 = *(const float4*)(im + a + 4);
        // half=1
        float A0r = r0.x + r0.y, A0i = q0.x + q0.y;
        float A1r = r0.x - r0.y, A1i = q0.x - q0.y;
        float A2r = r0.z + r0.w, A2i = q0.z + q0.w;
        float A3r = r0.z - r0.w, A3i = q0.z - q0.w;
        float B0r = r1.x + r1.y, B0i = q1.x + q1.y;
        float B1r = r1.x - r1.y, B1i = q1.x - q1.y;
        float B2r = r1.z + r1.w, B2i = q1.z + q1.w;
        float B3r = r1.z - r1.w, B3i = q1.z - q1.w;
        // half=2 ; twiddle on odd: *(+i)
        float t0r = A0r + A2r, t0i = A0i + A2i;
        float t2r = A0r - A2r, t2i = A0i - A2i;
        float w3r = -A3i, w3i = A3r;
        float t1r = A1r + w3r, t1i = A1i + w3i;
        float t3r = A1r - w3r, t3i = A1i - w3i;
        float u0r = B0r + B2r, u0i = B0i + B2i;
        float u2r = B0r - B2r, u2i = B0i - B2i;
        float x3r = -B3i, x3i = B3r;
        float u1r = B1r + x3r, u1i = B1i + x3i;
        float u3r = B1r - x3r, u3i = B1i - x3i;
        // half=4 ; twiddles 1, c(1+i), +i, c(-1+i)
        float w1r = RT2H * (u1r - u1i), w1i = RT2H * (u1r + u1i);
        float w2r = -u2i,               w2i = u2r;
        float w5r = RT2H * (-u3r - u3i), w5i = RT2H * (u3r - u3i);
        r0.x = t0r + u0r; q0.x = t0i + u0i;
        r1.x = t0r - u0r; q1.x = t0i - u0i;
        r0.y = t1r + w1r; q0.y = t1i + w1i;
        r1.y = t1r - w1r; q1.y = t1i - w1i;
        r0.z = t2r + w2r; q0.z = t2i + w2i;
        r1.z = t2r - w2r; q1.z = t2i - w2i;
        r0.w = t3r + w5r; q0.w = t3i + w5i;
        r1.w = t3r - w5r; q1.w = t3i - w5i;
        *(float4*)(re + a) = r0; *(float4*)(re + a + 4) = r1;
        *(float4*)(im + a) = q0; *(float4*)(im + a + 4) = q1;
    }
    __syncthreads();

    // --- radix-4 DIT stages ---
    r4_dit_stage<32>(re, im, tid);
    r4_dit_stage<128>(re, im, tid);
    r4_dit_stage<512>(re, im, tid);
    r4_dit_stage<2048>(re, im, tid);
    r4_dit_stage<8192>(re, im, tid);

    // --- fused final r2 DIT (half=8192) + store ---
    float2* oz = (float2*)(noise_out + (size_t)b * N_SAMPLES);
    #pragma unroll 1
    for (int s = 0; s < 8192 / NT; ++s) {
        int j = tid + s * NT;
        int a0 = MAP(j), a1 = MAP(j + 8192);
        float ur = re[a0], ui = im[a0];
        float xr = re[a1], xi = im[a1];
        float s1, c1; __sincosf((PI_F / 8192.0f) * (float)j, &s1, &c1);
        float wr = xr * c1 - xi * s1, wi = xr * s1 + xi * c1;
        oz[j] = make_float2(ur + wr, ui + wi);
        oz[j + 8192] = make_float2(ur - wr, ui - wi);
    }
}

// ---------------- K3: gate noise, add harmonic bank, sum 8 events ----------------
// Chebyshev: r_h = h*r_1, so sin((n+1)*r_h) = U-recurrence from one sincos.
__global__ __launch_bounds__(256) void assemble_kernel(
    const float* __restrict__ packed, const float* __restrict__ rW,
    const float* __restrict__ res, const float* __restrict__ noise_out,
    const float* __restrict__ oamp, float* __restrict__ out)
{
    const int g = blockIdx.y;
    const int chunk = blockIdx.x;
    const int tid = threadIdx.x;
    const int n = chunk * 256 + tid;
    const int fb = chunk - 1;

    __shared__ float s_res[8][8][3];
    __shared__ float s_ampf[8][3];
    __shared__ float s_r[8][8];
    if (tid < 192) {
        int e = tid / 24, rem = tid % 24, h = rem / 3, j = rem % 3;
        int f = min(max(fb + j, 0), 127);
        s_res[e][h][j] = res[((g * 8 + e) * 8 + h) * 128 + f];
    }
    if (tid < 24) {
        int e = tid / 3, j = tid % 3;
        int f = min(max(fb + j, 0), 127);
        s_ampf[e][j] = packed[(g * 8 + e) * PCK_STRIDE + 256 + f] * 2.0f - 1.0f;
    }
    if (tid >= 192 && tid < 256) {
        int u = tid - 192;
        s_r[u / 8][u % 8] = rW[g * 64 + u];
    }
    __syncthreads();

    float coords = ((float)n + 0.5f) * (1.0f / 256.0f) - 0.5f;
    coords = fminf(fmaxf(coords, 0.0f), 127.0f);
    int i0 = (int)floorf(coords);
    float w = coords - (float)i0;
    int j0 = i0 - fb;
    float osc50 = oamp[0];
    float pn = (float)(n + 1);
    float wm = 1.0f - w;

    float acc = 0.0f;
    #pragma unroll
    for (int e = 0; e < 8; ++e) {
        int b = g * 8 + e;
        float nv = noise_out[(size_t)b * N_SAMPLES + n];
        float av = s_ampf[e][j0] * wm + s_ampf[e][j0 + 1] * w;
        float gate = (av >= 0.0f) ? av : 0.2f * av;
        acc += nv * gate;
        float sn, cn; __sincosf(pn * s_r[e][0], &sn, &cn);
        float c2 = 2.0f * cn;
        float shm1 = 0.0f, sh = sn;
        #pragma unroll
        for (int h = 0; h < 8; ++h) {
            float rsv = s_res[e][h][j0] * wm + s_res[e][h][j0 + 1] * w;
            float sv = (s_r[e][h] != 0.0f) ? sh : 0.0f;
            acc += rsv * osc50 * sv;
            float nx = c2 * sh - shm1;
            shm1 = sh; sh = nx;
        }
    }
    out[(size_t)g * N_SAMPLES + n] = acc;
}

extern "C" void kernel_launch(void* const* d_in, const int* in_sizes, int n_in,
                              void* d_out, int out_size, void* d_ws, size_t ws_size,
                              hipStream_t stream) {
    const float* packed = (const float*)d_in[0];
    const float* freqs  = (const float*)d_in[1];
    const float* gamp   = (const float*)d_in[2];
    const float* oamp   = (const float*)d_in[3];
    const float* noise  = (const float*)d_in[4];
    float* out = (float*)d_out;

    float* ws = (float*)d_ws;
    float* noise_out = ws;
    float* res = ws + (size_t)B_EVENTS * N_SAMPLES;
    float* rW  = res + B_EVENTS * 8 * 128;

    fft_filter_kernel<<<B_EVENTS, NT, (2 * LDS_N + 16) * sizeof(float), stream>>>(
        noise, packed, gamp, noise_out, freqs, rW, res);
    assemble_kernel<<<dim3(N_SAMPLES / 256, N_GROUPS), 256, 0, stream>>>(
        packed, rW, res, noise_out, oamp, out);
}